// Round 15
// baseline (836.447 us; speedup 1.0000x reference)
//
#include <hip/hip_runtime.h>

// SpikeFP32GELUExact: x [2,2048,1024,32] f32 0/1 pulses (MSB-first bits of f32) ->
// pulses of fp32(GELU_fp64(value)).
//
// Wave-level repack: pack via __ballot (one v_cmp yields the full 32-bit words
// of TWO values), unpack via readlane+shift. Lane addressing is (lane^31) so
// MSB-first ordering falls out of ballot bit order with no bit-reverse; every
// access stays inside the same contiguous 256B block per instruction.
// (R8: __builtin_amdgcn_writelane doesn't exist in this ROCm -> use predicated
// selects to deposit the two ballot words into lanes 2r / 2r+1.)

__global__ __launch_bounds__(256) void spike_gelu_kernel(const float* __restrict__ in,
                                                         float* __restrict__ out,
                                                         int nvals) {
    const int tid  = blockIdx.x * blockDim.x + threadIdx.x;
    const int lane = threadIdx.x & 63;
    const int wave = tid >> 6;                  // each wave: 64 values = 2048 floats
    if (wave * 64 >= nvals) return;             // wave-granular guard (sizes are x64)

    const int lx = lane ^ 31;                   // reverse within each 32-lane half
    const size_t base = (size_t)wave * 2048;    // float offset of this wave's span
    const float* __restrict__ ip = in  + base + lx;
    float*       __restrict__ op = out + base + lx;

    // ---- pack: 32 ballot rounds; after them lane j holds value (wave*64 + j) ----
    // Round r, lane l reads pulse (64r + (l^31)): ballot low word == u32 of value
    // 2r, high word == u32 of value 2r+1 (MSB-first handled by ^31 addressing).
    unsigned int u = 0u;
#pragma unroll
    for (int r = 0; r < 32; ++r) {
        float f = ip[64 * r];                   // coalesced dword: 256B contiguous
        unsigned long long m = __ballot(f != 0.0f);
        unsigned int lo = (unsigned int)m;
        unsigned int hi = (unsigned int)(m >> 32);
        if (lane == 2 * r)     u = lo;          // v_cmp + cndmask (no writelane builtin)
        if (lane == 2 * r + 1) u = hi;
    }

    // ---- exact-FP64 GELU, matching the reference op-for-op ----
    {
#pragma clang fp contract(off)
        float xf = __uint_as_float(u);
        double vd = (double)xf;                 // exact f32->f64
        double x_sq = vd * vd;
        double x_cubed = x_sq * vd;
        double inner = vd + 0.044715 * x_cubed;
        double z = 0.7978845608028654 * inner;
        double e2z = exp(2.0 * z);              // 2.0*z exact (pow2 scale)
        double tanh_z = (e2z - 1.0) / (e2z + 1.0);
        double res64 = 0.5 * (vd * (1.0 + tanh_z));
        float rf = (float)res64;                // IEEE RN downcast
        u = __float_as_uint(rf);
    }

    // ---- unpack: inverse of pack; 2 readlane + select + shift + cvt per round ----
    const unsigned int sl = (unsigned int)(lane & 31);
    const bool hi_half = (lane >= 32);
#pragma unroll
    for (int r = 0; r < 32; ++r) {
        unsigned int s0 = __builtin_amdgcn_readlane(u, 2 * r);
        unsigned int s1 = __builtin_amdgcn_readlane(u, 2 * r + 1);
        unsigned int w  = hi_half ? s1 : s0;
        op[64 * r] = (float)((w >> sl) & 1u);   // coalesced dword store
    }
}

extern "C" void kernel_launch(void* const* d_in, const int* in_sizes, int n_in,
                              void* d_out, int out_size, void* d_ws, size_t ws_size,
                              hipStream_t stream) {
    const float* x = (const float*)d_in[0];
    float* out = (float*)d_out;
    int nvals = out_size / 32;                  // 4,194,304 values
    int block = 256;
    int grid = (nvals + block - 1) / block;     // 16384 blocks, 4 waves each
    spike_gelu_kernel<<<grid, block, 0, stream>>>(x, out, nvals);
}